// Round 1
// baseline (863.727 us; speedup 1.0000x reference)
//
#include <hip/hip_runtime.h>
#include <math.h>

#define T_ 250
#define BL 2000        // 8 * 250
#define KIN 480        // P*F = 20*24
#define NFLAT 120000   // 24*5000

__device__ __forceinline__ float sigmoidf_(float x){ return 1.0f/(1.0f+expf(-x)); }
__device__ __forceinline__ float siluf_(float x){ return x*sigmoidf_(x); }
__device__ __forceinline__ float softplusf_(float x){ return (x > 20.0f) ? x : log1pf(expf(x)); }
__device__ __forceinline__ float seluf_(float x){
  const float sc = 1.0507009873554804934193349852946f;
  const float al = 1.6732632423543772848170429916717f;
  return x > 0.0f ? sc*x : sc*al*expm1f(x);
}

// ---------------------------------------------------------------------------
// Generic fp32 tiled GEMM: C[M,N] = A[M,K] * W[N,K]^T  (both row-major, K contig)
// epi: 0 = store, 1 = store softplus(acc + bias[n]), 2 = store selu(acc),
//      3 = atomicAdd (for split-K; C must be pre-zeroed)
// ---------------------------------------------------------------------------
template<int BM, int BN, int BK, int TM, int TN>
__global__ __launch_bounds__(256, 2) void gemm_nt(
    const float* __restrict__ A, const float* __restrict__ W,
    float* __restrict__ C, const float* __restrict__ bias,
    int M, int N, int K, int lda, int ldb, int ldc, int epi)
{
  static_assert(BK == 32, "BK must be 32");
  __shared__ float As[BK][BM + 4];
  __shared__ float Bs[BK][BN + 4];
  constexpr int TNX = BN / TN;
  constexpr int TMX = BM / TM;
  static_assert(TNX * TMX == 256, "256 threads required");
  constexpr int AF4 = BM * BK / 1024;   // float4 loads per thread for A tile
  constexpr int BF4 = BN * BK / 1024;

  const int tid = threadIdx.x;
  const int tx = tid % TNX;
  const int ty = tid / TNX;
  const int m0 = blockIdx.y * BM;
  const int n0 = blockIdx.x * BN;
  const int kchunk = K / (int)gridDim.z;
  const int k_begin = blockIdx.z * kchunk;
  const int k_end = k_begin + kchunk;

  float acc[TM][TN];
#pragma unroll
  for (int i = 0; i < TM; ++i)
#pragma unroll
    for (int j = 0; j < TN; ++j) acc[i][j] = 0.0f;

  for (int k0 = k_begin; k0 < k_end; k0 += BK) {
#pragma unroll
    for (int i = 0; i < AF4; ++i) {
      int fi = tid + 256 * i;
      int r = fi >> 3;               // BK/4 == 8 float4 per row
      int kc = (fi & 7) * 4;
      int m = m0 + r;
      float4 v = make_float4(0.f, 0.f, 0.f, 0.f);
      if (m < M) v = *(const float4*)(A + (size_t)m * lda + k0 + kc);
      As[kc + 0][r] = v.x; As[kc + 1][r] = v.y; As[kc + 2][r] = v.z; As[kc + 3][r] = v.w;
    }
#pragma unroll
    for (int i = 0; i < BF4; ++i) {
      int fi = tid + 256 * i;
      int r = fi >> 3;
      int kc = (fi & 7) * 4;
      int n = n0 + r;
      float4 v = make_float4(0.f, 0.f, 0.f, 0.f);
      if (n < N) v = *(const float4*)(W + (size_t)n * ldb + k0 + kc);
      Bs[kc + 0][r] = v.x; Bs[kc + 1][r] = v.y; Bs[kc + 2][r] = v.z; Bs[kc + 3][r] = v.w;
    }
    __syncthreads();
#pragma unroll
    for (int kk = 0; kk < BK; ++kk) {
      float a[TM], bb[TN];
#pragma unroll
      for (int i = 0; i < TM; ++i) a[i] = As[kk][ty * TM + i];
#pragma unroll
      for (int j = 0; j < TN; ++j) bb[j] = Bs[kk][tx * TN + j];
#pragma unroll
      for (int i = 0; i < TM; ++i)
#pragma unroll
        for (int j = 0; j < TN; ++j) acc[i][j] = fmaf(a[i], bb[j], acc[i][j]);
    }
    __syncthreads();
  }

#pragma unroll
  for (int i = 0; i < TM; ++i) {
    int m = m0 + ty * TM + i;
    if (m >= M) continue;
#pragma unroll
    for (int j = 0; j < TN; ++j) {
      int n = n0 + tx * TN + j;
      if (n >= N) continue;
      float v = acc[i][j];
      if (epi == 1) v = softplusf_(v + bias[n]);
      else if (epi == 2) v = seluf_(v);
      if (epi == 3) atomicAdd(&C[(size_t)m * ldc + n], v);
      else C[(size_t)m * ldc + n] = v;
    }
  }
}

// ---------------------------------------------------------------------------
// Depthwise causal conv1d (width 4) + bias + silu.  xz x-half -> xc
// ---------------------------------------------------------------------------
__global__ __launch_bounds__(256) void conv_silu(
    const float* __restrict__ xz, const float* __restrict__ cw,
    const float* __restrict__ cb, float* __restrict__ xc)
{
  int id = blockIdx.x * 256 + threadIdx.x;
  if (id >= BL * 1024) return;
  int bl = id >> 10;
  int d = id & 1023;
  int l = bl % T_;
  float4 w4 = *(const float4*)(cw + d * 4);
  float s = cb[d];
  if (l >= 3) s = fmaf(xz[(size_t)(bl - 3) * 2048 + d], w4.x, s);
  if (l >= 2) s = fmaf(xz[(size_t)(bl - 2) * 2048 + d], w4.y, s);
  if (l >= 1) s = fmaf(xz[(size_t)(bl - 1) * 2048 + d], w4.z, s);
  s = fmaf(xz[(size_t)bl * 2048 + d], w4.w, s);
  xc[id] = siluf_(s);
}

// ---------------------------------------------------------------------------
// Selective scan. Wave = 4 channels x (16 lanes x 4 states).
// Writes gated output into xz x-half (cols 0..1023), reads z from cols 1024+.
// ---------------------------------------------------------------------------
__global__ __launch_bounds__(256) void scan_kernel(
    const float* __restrict__ dtb, const float* __restrict__ xc,
    const float* __restrict__ xdbl, float* __restrict__ xz,
    const float* __restrict__ A_log, const float* __restrict__ Dp)
{
  int tid = threadIdx.x;
  int wv = tid >> 6, lane = tid & 63;
  int g = lane >> 4, q = lane & 15;
  int blk = blockIdx.x;            // 512 blocks: 8 b x 64 groups of 16 channels
  int b = blk >> 6;
  int d = ((blk & 63) << 4) + wv * 4 + g;
  int s0 = q * 4;
  const float LOG2E = 1.4426950408889634f;
  float4 al = *(const float4*)(A_log + (size_t)d * 64 + s0);
  float am0 = -expf(al.x) * LOG2E;
  float am1 = -expf(al.y) * LOG2E;
  float am2 = -expf(al.z) * LOG2E;
  float am3 = -expf(al.w) * LOG2E;
  float Dv = Dp[d];
  float h0 = 0.f, h1 = 0.f, h2 = 0.f, h3 = 0.f;
  const float* dtp = dtb + (size_t)b * T_ * 1024 + d;
  const float* xp  = xc  + (size_t)b * T_ * 1024 + d;
  const float* zp  = xz  + (size_t)b * T_ * 2048 + 1024 + d;
  float*       yp  = xz  + (size_t)b * T_ * 2048 + d;
  const float* bp  = xdbl + (size_t)b * T_ * 160 + 32 + s0;
  const float* cp  = bp + 64;
  for (int l = 0; l < T_; ++l) {
    float dt = dtp[(size_t)l * 1024];
    float xv = xp[(size_t)l * 1024];
    float zv = zp[(size_t)l * 2048];
    float4 Bv = *(const float4*)(bp + (size_t)l * 160);
    float4 Cv = *(const float4*)(cp + (size_t)l * 160);
    float dtx = dt * xv;
    h0 = fmaf(h0, exp2f(dt * am0), dtx * Bv.x);
    h1 = fmaf(h1, exp2f(dt * am1), dtx * Bv.y);
    h2 = fmaf(h2, exp2f(dt * am2), dtx * Bv.z);
    h3 = fmaf(h3, exp2f(dt * am3), dtx * Bv.w);
    float p = fmaf(h0, Cv.x, fmaf(h1, Cv.y, fmaf(h2, Cv.z, h3 * Cv.w)));
    p += __shfl_xor(p, 1);
    p += __shfl_xor(p, 2);
    p += __shfl_xor(p, 4);
    p += __shfl_xor(p, 8);
    if (q == 0) {
      float yv = fmaf(xv, Dv, p);
      float sz = zv * sigmoidf_(zv);
      yp[(size_t)l * 2048] = yv * sz;
    }
  }
}

// ---------------------------------------------------------------------------
// Permute selu(out_proj) [2000][480] -> y_flat [8][120000] (f-major)
// ---------------------------------------------------------------------------
__global__ __launch_bounds__(256) void transpose_k(
    const float* __restrict__ ym, float* __restrict__ yfl)
{
  int id = blockIdx.x * 256 + threadIdx.x;
  if (id >= 8 * NFLAT) return;
  int b = id / NFLAT;
  int r = id % NFLAT;
  int f = r / 5000;
  int qq = r % 5000;
  int tt = qq / 20;
  int p = qq % 20;
  yfl[id] = ym[(size_t)(b * T_ + tt) * KIN + p * 24 + f];
}

// ---------------------------------------------------------------------------
// fc1: r1[b][c] += sum_k yfl[b][k] * W1[c][k].  512 blocks = 64 c-groups x 8 k-slices.
// Each wave owns 2 c rows (c-pair), accumulates 8 batches; butterfly + atomicAdd.
// ---------------------------------------------------------------------------
__global__ __launch_bounds__(256) void fc1_kernel(
    const float* __restrict__ yfl, const float* __restrict__ W,
    float* __restrict__ r1)
{
  int blk = blockIdx.x;
  int ks = blk & 7;            // k slice (15000 each)
  int cg = blk >> 3;           // 0..63 -> c0 = cg*8
  int wv = threadIdx.x >> 6;
  int lane = threadIdx.x & 63;
  int ca = cg * 8 + wv * 2;
  const float* Wa = W + (size_t)ca * NFLAT;
  const float* Wb = W + (size_t)(ca + 1) * NFLAT;
  float acc[2][8];
#pragma unroll
  for (int c = 0; c < 2; ++c)
#pragma unroll
    for (int b = 0; b < 8; ++b) acc[c][b] = 0.0f;

  int kbase = ks * 15000;
  for (int k = kbase + lane * 4; k < kbase + 15000; k += 256) {
    float4 wa = *(const float4*)(Wa + k);
    float4 wb = *(const float4*)(Wb + k);
#pragma unroll
    for (int b = 0; b < 8; ++b) {
      float4 y = *(const float4*)(yfl + (size_t)b * NFLAT + k);
      acc[0][b] = fmaf(wa.x, y.x, fmaf(wa.y, y.y, fmaf(wa.z, y.z, fmaf(wa.w, y.w, acc[0][b]))));
      acc[1][b] = fmaf(wb.x, y.x, fmaf(wb.y, y.y, fmaf(wb.z, y.z, fmaf(wb.w, y.w, acc[1][b]))));
    }
  }
#pragma unroll
  for (int c = 0; c < 2; ++c)
#pragma unroll
    for (int b = 0; b < 8; ++b) {
      float s = acc[c][b];
      s += __shfl_xor(s, 1);
      s += __shfl_xor(s, 2);
      s += __shfl_xor(s, 4);
      s += __shfl_xor(s, 8);
      s += __shfl_xor(s, 16);
      s += __shfl_xor(s, 32);
      if (lane == 0) atomicAdd(&r1[b * 512 + ca + c], s);
    }
}

// ---------------------------------------------------------------------------
// fc2: one wave per output (b,j): dot-512 + biases
// ---------------------------------------------------------------------------
__global__ __launch_bounds__(256) void fc2_kernel(
    const float* __restrict__ r1, const float* __restrict__ b1,
    const float* __restrict__ W2, const float* __restrict__ b2,
    float* __restrict__ r2)
{
  int wid = blockIdx.x * 4 + (threadIdx.x >> 6);   // 0..2047
  int lane = threadIdx.x & 63;
  int b = wid >> 8;
  int j = wid & 255;
  int off = lane * 8;
  float4 ya = *(const float4*)(r1 + b * 512 + off);
  float4 yb = *(const float4*)(r1 + b * 512 + off + 4);
  float4 ba = *(const float4*)(b1 + off);
  float4 bbv = *(const float4*)(b1 + off + 4);
  float4 wa = *(const float4*)(W2 + (size_t)j * 512 + off);
  float4 wb = *(const float4*)(W2 + (size_t)j * 512 + off + 4);
  float p = (ya.x + ba.x) * wa.x + (ya.y + ba.y) * wa.y +
            (ya.z + ba.z) * wa.z + (ya.w + ba.w) * wa.w +
            (yb.x + bbv.x) * wb.x + (yb.y + bbv.y) * wb.y +
            (yb.z + bbv.z) * wb.z + (yb.w + bbv.w) * wb.w;
  p += __shfl_xor(p, 1);
  p += __shfl_xor(p, 2);
  p += __shfl_xor(p, 4);
  p += __shfl_xor(p, 8);
  p += __shfl_xor(p, 16);
  p += __shfl_xor(p, 32);
  if (lane == 0) r2[b * 256 + j] = p + b2[j];
}

// ---------------------------------------------------------------------------
// fc3 + fc4 fused, single block
// ---------------------------------------------------------------------------
__global__ __launch_bounds__(256) void fc34_kernel(
    const float* __restrict__ r2, const float* __restrict__ W3,
    const float* __restrict__ b3, const float* __restrict__ W4,
    const float* __restrict__ b4, float* __restrict__ out)
{
  __shared__ float a3[512];
  int tid = threadIdx.x;
  for (int o = tid; o < 512; o += 256) {
    int b = o >> 6, j = o & 63;
    float s = b3[j];
    const float* rr = r2 + b * 256;
    const float* wr = W3 + j * 256;
    for (int c = 0; c < 256; c += 4) {
      float4 rv = *(const float4*)(rr + c);
      float4 wv = *(const float4*)(wr + c);
      s = fmaf(rv.x, wv.x, fmaf(rv.y, wv.y, fmaf(rv.z, wv.z, fmaf(rv.w, wv.w, s))));
    }
    a3[o] = s;
  }
  __syncthreads();
  if (tid < 64) {
    int b = tid >> 3, j = tid & 7;
    float s = b4[j];
    const float* ar = a3 + b * 64;
    const float* wr = W4 + j * 64;
    for (int c = 0; c < 64; ++c) s = fmaf(ar[c], wr[c], s);
    out[b * 8 + j] = s;
  }
}

// ---------------------------------------------------------------------------
extern "C" void kernel_launch(void* const* d_in, const int* in_sizes, int n_in,
                              void* d_out, int out_size, void* d_ws, size_t ws_size,
                              hipStream_t stream) {
  const float* x      = (const float*)d_in[0];   // [8,5000,24] == [2000][480]
  const float* w_in   = (const float*)d_in[1];   // [2048,512]
  const float* conv_w = (const float*)d_in[2];   // [1024,4]
  const float* conv_b = (const float*)d_in[3];   // [1024]
  const float* w_xp   = (const float*)d_in[4];   // [160,1024]
  const float* w_dt   = (const float*)d_in[5];   // [1024,32]
  const float* b_dt   = (const float*)d_in[6];   // [1024]
  const float* A_log  = (const float*)d_in[7];   // [1024,64]
  const float* Dp     = (const float*)d_in[8];   // [1024]
  const float* w_out  = (const float*)d_in[9];   // [512,1024]
  const float* w1 = (const float*)d_in[10];      // [512,120000]
  const float* b1 = (const float*)d_in[11];
  const float* w2 = (const float*)d_in[12];      // [256,512]
  const float* b2 = (const float*)d_in[13];
  const float* w3 = (const float*)d_in[14];      // [64,256]
  const float* b3 = (const float*)d_in[15];
  const float* w4 = (const float*)d_in[16];      // [8,64]
  const float* b4 = (const float*)d_in[17];
  float* out = (float*)d_out;

  float* ws   = (float*)d_ws;
  float* xz   = ws;                 // [2000][2048]  (x-half becomes gated-y later)
  float* xc   = xz + 4096000;       // [2000][1024]
  float* dtb  = xc + 2048000;       // [2000][1024]
  float* ym   = dtb + 2048000;      // [2000][480]
  float* yfl  = ym + 960000;        // [8][120000]
  float* xdbl = yfl + 960000;       // [2000][160]
  float* r1   = xdbl + 320000;      // [8][512]
  // total: 10,436,096 floats + 2048 (r2) ~= 41.8 MB
  float* r2   = r1 + 4096;          // [8][256]

  // zero the atomic accumulators (xdbl + r1, contiguous)
  hipMemsetAsync(xdbl, 0, (320000 + 4096) * sizeof(float), stream);

  // 1. in_proj: xz[2000][2048] = x[2000][480] @ Win[2048][512(^480)]^T
  gemm_nt<64, 128, 32, 4, 8><<<dim3(2048 / 128, (BL + 63) / 64, 1), 256, 0, stream>>>(
      x, w_in, xz, nullptr, BL, 2048, KIN, KIN, 512, 2048, 0);

  // 2. depthwise conv + silu
  conv_silu<<<(BL * 1024) / 256, 256, 0, stream>>>(xz, conv_w, conv_b, xc);

  // 3. x_proj (split-K=2, atomic): xdbl[2000][160] = xc @ Wxp^T
  gemm_nt<32, 64, 32, 1, 8><<<dim3(3, (BL + 31) / 32, 2), 256, 0, stream>>>(
      xc, w_xp, xdbl, nullptr, BL, 160, 1024, 1024, 1024, 160, 3);

  // 4. dt_proj + softplus: dtb[2000][1024] = softplus(xdbl[:, :32] @ Wdt^T + b_dt)
  gemm_nt<32, 64, 32, 1, 8><<<dim3(1024 / 64, (BL + 31) / 32, 1), 256, 0, stream>>>(
      xdbl, w_dt, dtb, b_dt, BL, 1024, 32, 160, 32, 1024, 1);

  // 5. selective scan -> gated y into xz x-half
  scan_kernel<<<512, 256, 0, stream>>>(dtb, xc, xdbl, xz, A_log, Dp);

  // 6. out_proj + selu: ym[2000][480] = selu(yg @ Wout[480 rows]^T)
  gemm_nt<64, 64, 32, 4, 4><<<dim3((KIN + 63) / 64, (BL + 63) / 64, 1), 256, 0, stream>>>(
      xz, w_out, ym, nullptr, BL, KIN, 1024, 2048, 1024, KIN, 2);

  // 7. permute to y_flat
  transpose_k<<<(8 * NFLAT) / 256, 256, 0, stream>>>(ym, yfl);

  // 8. fc1 (atomic accumulate into r1)
  fc1_kernel<<<512, 256, 0, stream>>>(yfl, w1, r1);

  // 9. fc2
  fc2_kernel<<<512, 256, 0, stream>>>(r1, b1, w2, b2, r2);

  // 10. fc3 + fc4
  fc34_kernel<<<1, 256, 0, stream>>>(r2, w3, b3, w4, b4, out);
}

// Round 2
// 765.621 us; speedup vs baseline: 1.1281x; 1.1281x over previous
//
#include <hip/hip_runtime.h>
#include <math.h>

#define T_ 250
#define BL 2000        // 8 * 250
#define KIN 480        // P*F = 20*24
#define NFLAT 120000   // 24*5000

__device__ __forceinline__ float sigmoidf_(float x){ return 1.0f/(1.0f+expf(-x)); }
__device__ __forceinline__ float siluf_(float x){ return x*sigmoidf_(x); }
__device__ __forceinline__ float softplusf_(float x){ return (x > 20.0f) ? x : log1pf(expf(x)); }
__device__ __forceinline__ float seluf_(float x){
  const float sc = 1.0507009873554804934193349852946f;
  const float al = 1.6732632423543772848170429916717f;
  return x > 0.0f ? sc*x : sc*al*expm1f(x);
}

// DPP-based add: s + dpp_move(s). Runs on the VALU pipe (no LDS round-trip).
// CTRL: 0xB1 = quad_perm xor1, 0x4E = quad_perm xor2, 0x124 = row_ror:4, 0x128 = row_ror:8
template<int CTRL>
__device__ __forceinline__ float dpp_add(float x) {
  int t = __builtin_amdgcn_update_dpp(0, __builtin_bit_cast(int, x), CTRL, 0xF, 0xF, true);
  return x + __builtin_bit_cast(float, t);
}

// ---------------------------------------------------------------------------
// Generic fp32 tiled GEMM: C[M,N] = A[M,K] * W[N,K]^T  (both row-major, K contig)
// epi: 0 = store, 1 = store softplus(acc + bias[n]), 2 = store selu(acc),
//      3 = atomicAdd (for split-K; C must be pre-zeroed)
// ---------------------------------------------------------------------------
template<int BM, int BN, int BK, int TM, int TN>
__global__ __launch_bounds__(256, 2) void gemm_nt(
    const float* __restrict__ A, const float* __restrict__ W,
    float* __restrict__ C, const float* __restrict__ bias,
    int M, int N, int K, int lda, int ldb, int ldc, int epi)
{
  static_assert(BK == 32, "BK must be 32");
  __shared__ float As[BK][BM + 4];
  __shared__ float Bs[BK][BN + 4];
  constexpr int TNX = BN / TN;
  constexpr int TMX = BM / TM;
  static_assert(TNX * TMX == 256, "256 threads required");
  constexpr int AF4 = BM * BK / 1024;   // float4 loads per thread for A tile
  constexpr int BF4 = BN * BK / 1024;

  const int tid = threadIdx.x;
  const int tx = tid % TNX;
  const int ty = tid / TNX;
  const int m0 = blockIdx.y * BM;
  const int n0 = blockIdx.x * BN;
  const int kchunk = K / (int)gridDim.z;
  const int k_begin = blockIdx.z * kchunk;
  const int k_end = k_begin + kchunk;

  float acc[TM][TN];
#pragma unroll
  for (int i = 0; i < TM; ++i)
#pragma unroll
    for (int j = 0; j < TN; ++j) acc[i][j] = 0.0f;

  for (int k0 = k_begin; k0 < k_end; k0 += BK) {
#pragma unroll
    for (int i = 0; i < AF4; ++i) {
      int fi = tid + 256 * i;
      int r = fi >> 3;               // BK/4 == 8 float4 per row
      int kc = (fi & 7) * 4;
      int m = m0 + r;
      float4 v = make_float4(0.f, 0.f, 0.f, 0.f);
      if (m < M) v = *(const float4*)(A + (size_t)m * lda + k0 + kc);
      As[kc + 0][r] = v.x; As[kc + 1][r] = v.y; As[kc + 2][r] = v.z; As[kc + 3][r] = v.w;
    }
#pragma unroll
    for (int i = 0; i < BF4; ++i) {
      int fi = tid + 256 * i;
      int r = fi >> 3;
      int kc = (fi & 7) * 4;
      int n = n0 + r;
      float4 v = make_float4(0.f, 0.f, 0.f, 0.f);
      if (n < N) v = *(const float4*)(W + (size_t)n * ldb + k0 + kc);
      Bs[kc + 0][r] = v.x; Bs[kc + 1][r] = v.y; Bs[kc + 2][r] = v.z; Bs[kc + 3][r] = v.w;
    }
    __syncthreads();
#pragma unroll
    for (int kk = 0; kk < BK; ++kk) {
      float a[TM], bb[TN];
#pragma unroll
      for (int i = 0; i < TM; ++i) a[i] = As[kk][ty * TM + i];
#pragma unroll
      for (int j = 0; j < TN; ++j) bb[j] = Bs[kk][tx * TN + j];
#pragma unroll
      for (int i = 0; i < TM; ++i)
#pragma unroll
        for (int j = 0; j < TN; ++j) acc[i][j] = fmaf(a[i], bb[j], acc[i][j]);
    }
    __syncthreads();
  }

#pragma unroll
  for (int i = 0; i < TM; ++i) {
    int m = m0 + ty * TM + i;
    if (m >= M) continue;
#pragma unroll
    for (int j = 0; j < TN; ++j) {
      int n = n0 + tx * TN + j;
      if (n >= N) continue;
      float v = acc[i][j];
      if (epi == 1) v = softplusf_(v + bias[n]);
      else if (epi == 2) v = seluf_(v);
      if (epi == 3) atomicAdd(&C[(size_t)m * ldc + n], v);
      else C[(size_t)m * ldc + n] = v;
    }
  }
}

// ---------------------------------------------------------------------------
// Depthwise causal conv1d (width 4) + bias + silu.  xz x-half -> xc
// ---------------------------------------------------------------------------
__global__ __launch_bounds__(256) void conv_silu(
    const float* __restrict__ xz, const float* __restrict__ cw,
    const float* __restrict__ cb, float* __restrict__ xc)
{
  int id = blockIdx.x * 256 + threadIdx.x;
  if (id >= BL * 1024) return;
  int bl = id >> 10;
  int d = id & 1023;
  int l = bl % T_;
  float4 w4 = *(const float4*)(cw + d * 4);
  float s = cb[d];
  if (l >= 3) s = fmaf(xz[(size_t)(bl - 3) * 2048 + d], w4.x, s);
  if (l >= 2) s = fmaf(xz[(size_t)(bl - 2) * 2048 + d], w4.y, s);
  if (l >= 1) s = fmaf(xz[(size_t)(bl - 1) * 2048 + d], w4.z, s);
  s = fmaf(xz[(size_t)bl * 2048 + d], w4.w, s);
  xc[id] = siluf_(s);
}

// ---------------------------------------------------------------------------
// Selective scan. Wave = 4 channels (one per DPP row) x (16 lanes x 4 states).
// Reduction over the 16 lanes of a row via 4 DPP adds (VALU pipe, no LDS).
// Loads software-pipelined 2 steps deep.
// Writes gated output into xz x-half (cols 0..1023), reads z from cols 1024+.
// ---------------------------------------------------------------------------
__global__ __launch_bounds__(256) void scan_kernel(
    const float* __restrict__ dtb, const float* __restrict__ xc,
    const float* __restrict__ xdbl, float* __restrict__ xz,
    const float* __restrict__ A_log, const float* __restrict__ Dp)
{
  int tid = threadIdx.x;
  int wv = tid >> 6, lane = tid & 63;
  int g = lane >> 4, q = lane & 15;
  int blk = blockIdx.x;            // 512 blocks: 8 b x 64 groups of 16 channels
  int b = blk >> 6;
  int d = ((blk & 63) << 4) + wv * 4 + g;
  int s0 = q * 4;
  const float LOG2E = 1.4426950408889634f;
  float4 al = *(const float4*)(A_log + (size_t)d * 64 + s0);
  float am0 = -expf(al.x) * LOG2E;
  float am1 = -expf(al.y) * LOG2E;
  float am2 = -expf(al.z) * LOG2E;
  float am3 = -expf(al.w) * LOG2E;
  float Dv = Dp[d];
  float h0 = 0.f, h1 = 0.f, h2 = 0.f, h3 = 0.f;
  const float* dtp = dtb + (size_t)b * T_ * 1024 + d;
  const float* xp  = xc  + (size_t)b * T_ * 1024 + d;
  const float* zp  = xz  + (size_t)b * T_ * 2048 + 1024 + d;
  float*       yp  = xz  + (size_t)b * T_ * 2048 + d;
  const float* bp  = xdbl + (size_t)b * T_ * 160 + 32 + s0;
  const float* cp  = bp + 64;

  // depth-2 prefetch ring
  float dt_f[2], xv_f[2], zv_f[2];
  float4 B_f[2], C_f[2];
#pragma unroll
  for (int i = 0; i < 2; ++i) {
    dt_f[i] = dtp[(size_t)i * 1024];
    xv_f[i] = xp[(size_t)i * 1024];
    zv_f[i] = zp[(size_t)i * 2048];
    B_f[i] = *(const float4*)(bp + (size_t)i * 160);
    C_f[i] = *(const float4*)(cp + (size_t)i * 160);
  }

#pragma unroll 2
  for (int l = 0; l < T_; ++l) {
    int slot = l & 1;
    // consume step l (waits on loads issued 2 iterations ago)
    float dt = dt_f[slot], xv = xv_f[slot], zv = zv_f[slot];
    float4 Bv = B_f[slot], Cv = C_f[slot];
    // issue loads for step l+2
    int lp = (l + 2 < T_) ? l + 2 : T_ - 1;
    dt_f[slot] = dtp[(size_t)lp * 1024];
    xv_f[slot] = xp[(size_t)lp * 1024];
    zv_f[slot] = zp[(size_t)lp * 2048];
    B_f[slot] = *(const float4*)(bp + (size_t)lp * 160);
    C_f[slot] = *(const float4*)(cp + (size_t)lp * 160);

    float dtx = dt * xv;
    h0 = fmaf(h0, exp2f(dt * am0), dtx * Bv.x);
    h1 = fmaf(h1, exp2f(dt * am1), dtx * Bv.y);
    h2 = fmaf(h2, exp2f(dt * am2), dtx * Bv.z);
    h3 = fmaf(h3, exp2f(dt * am3), dtx * Bv.w);
    float p = fmaf(h0, Cv.x, fmaf(h1, Cv.y, fmaf(h2, Cv.z, h3 * Cv.w)));
    // all-lanes row (16-lane) sum on the VALU pipe
    p = dpp_add<0xB1>(p);    // quad_perm [1,0,3,2]  (xor 1)
    p = dpp_add<0x4E>(p);    // quad_perm [2,3,0,1]  (xor 2)
    p = dpp_add<0x124>(p);   // row_ror:4
    p = dpp_add<0x128>(p);   // row_ror:8
    float yv = fmaf(xv, Dv, p);
    float sz = zv * sigmoidf_(zv);
    if (q == 0) yp[(size_t)l * 2048] = yv * sz;
  }
}

// ---------------------------------------------------------------------------
// Permute selu(out_proj) [2000][480] -> y_flat [8][120000] (f-major)
// ---------------------------------------------------------------------------
__global__ __launch_bounds__(256) void transpose_k(
    const float* __restrict__ ym, float* __restrict__ yfl)
{
  int id = blockIdx.x * 256 + threadIdx.x;
  if (id >= 8 * NFLAT) return;
  int b = id / NFLAT;
  int r = id % NFLAT;
  int f = r / 5000;
  int qq = r % 5000;
  int tt = qq / 20;
  int p = qq % 20;
  yfl[id] = ym[(size_t)(b * T_ + tt) * KIN + p * 24 + f];
}

// ---------------------------------------------------------------------------
// fc1: r1[b][c] += sum_k yfl[b][k] * W1[c][k].  512 blocks = 64 c-groups x 8 k-slices.
// Each wave owns 2 c rows (c-pair), accumulates 8 batches; butterfly + atomicAdd.
// ---------------------------------------------------------------------------
__global__ __launch_bounds__(256) void fc1_kernel(
    const float* __restrict__ yfl, const float* __restrict__ W,
    float* __restrict__ r1)
{
  int blk = blockIdx.x;
  int ks = blk & 7;            // k slice (15000 each)
  int cg = blk >> 3;           // 0..63 -> c0 = cg*8
  int wv = threadIdx.x >> 6;
  int lane = threadIdx.x & 63;
  int ca = cg * 8 + wv * 2;
  const float* Wa = W + (size_t)ca * NFLAT;
  const float* Wb = W + (size_t)(ca + 1) * NFLAT;
  float acc[2][8];
#pragma unroll
  for (int c = 0; c < 2; ++c)
#pragma unroll
    for (int b = 0; b < 8; ++b) acc[c][b] = 0.0f;

  int kbase = ks * 15000;
  for (int k = kbase + lane * 4; k < kbase + 15000; k += 256) {
    float4 wa = *(const float4*)(Wa + k);
    float4 wb = *(const float4*)(Wb + k);
#pragma unroll
    for (int b = 0; b < 8; ++b) {
      float4 y = *(const float4*)(yfl + (size_t)b * NFLAT + k);
      acc[0][b] = fmaf(wa.x, y.x, fmaf(wa.y, y.y, fmaf(wa.z, y.z, fmaf(wa.w, y.w, acc[0][b]))));
      acc[1][b] = fmaf(wb.x, y.x, fmaf(wb.y, y.y, fmaf(wb.z, y.z, fmaf(wb.w, y.w, acc[1][b]))));
    }
  }
#pragma unroll
  for (int c = 0; c < 2; ++c)
#pragma unroll
    for (int b = 0; b < 8; ++b) {
      float s = acc[c][b];
      s += __shfl_xor(s, 1);
      s += __shfl_xor(s, 2);
      s += __shfl_xor(s, 4);
      s += __shfl_xor(s, 8);
      s += __shfl_xor(s, 16);
      s += __shfl_xor(s, 32);
      if (lane == 0) atomicAdd(&r1[b * 512 + ca + c], s);
    }
}

// ---------------------------------------------------------------------------
// fc2: one wave per output (b,j): dot-512 + biases
// ---------------------------------------------------------------------------
__global__ __launch_bounds__(256) void fc2_kernel(
    const float* __restrict__ r1, const float* __restrict__ b1,
    const float* __restrict__ W2, const float* __restrict__ b2,
    float* __restrict__ r2)
{
  int wid = blockIdx.x * 4 + (threadIdx.x >> 6);   // 0..2047
  int lane = threadIdx.x & 63;
  int b = wid >> 8;
  int j = wid & 255;
  int off = lane * 8;
  float4 ya = *(const float4*)(r1 + b * 512 + off);
  float4 yb = *(const float4*)(r1 + b * 512 + off + 4);
  float4 ba = *(const float4*)(b1 + off);
  float4 bbv = *(const float4*)(b1 + off + 4);
  float4 wa = *(const float4*)(W2 + (size_t)j * 512 + off);
  float4 wb = *(const float4*)(W2 + (size_t)j * 512 + off + 4);
  float p = (ya.x + ba.x) * wa.x + (ya.y + ba.y) * wa.y +
            (ya.z + ba.z) * wa.z + (ya.w + ba.w) * wa.w +
            (yb.x + bbv.x) * wb.x + (yb.y + bbv.y) * wb.y +
            (yb.z + bbv.z) * wb.z + (yb.w + bbv.w) * wb.w;
  p += __shfl_xor(p, 1);
  p += __shfl_xor(p, 2);
  p += __shfl_xor(p, 4);
  p += __shfl_xor(p, 8);
  p += __shfl_xor(p, 16);
  p += __shfl_xor(p, 32);
  if (lane == 0) r2[b * 256 + j] = p + b2[j];
}

// ---------------------------------------------------------------------------
// fc3 + fc4 fused, single block
// ---------------------------------------------------------------------------
__global__ __launch_bounds__(256) void fc34_kernel(
    const float* __restrict__ r2, const float* __restrict__ W3,
    const float* __restrict__ b3, const float* __restrict__ W4,
    const float* __restrict__ b4, float* __restrict__ out)
{
  __shared__ float a3[512];
  int tid = threadIdx.x;
  for (int o = tid; o < 512; o += 256) {
    int b = o >> 6, j = o & 63;
    float s = b3[j];
    const float* rr = r2 + b * 256;
    const float* wr = W3 + j * 256;
    for (int c = 0; c < 256; c += 4) {
      float4 rv = *(const float4*)(rr + c);
      float4 wv = *(const float4*)(wr + c);
      s = fmaf(rv.x, wv.x, fmaf(rv.y, wv.y, fmaf(rv.z, wv.z, fmaf(rv.w, wv.w, s))));
    }
    a3[o] = s;
  }
  __syncthreads();
  if (tid < 64) {
    int b = tid >> 3, j = tid & 7;
    float s = b4[j];
    const float* ar = a3 + b * 64;
    const float* wr = W4 + j * 64;
    for (int c = 0; c < 64; ++c) s = fmaf(ar[c], wr[c], s);
    out[b * 8 + j] = s;
  }
}

// ---------------------------------------------------------------------------
extern "C" void kernel_launch(void* const* d_in, const int* in_sizes, int n_in,
                              void* d_out, int out_size, void* d_ws, size_t ws_size,
                              hipStream_t stream) {
  const float* x      = (const float*)d_in[0];   // [8,5000,24] == [2000][480]
  const float* w_in   = (const float*)d_in[1];   // [2048,512]
  const float* conv_w = (const float*)d_in[2];   // [1024,4]
  const float* conv_b = (const float*)d_in[3];   // [1024]
  const float* w_xp   = (const float*)d_in[4];   // [160,1024]
  const float* w_dt   = (const float*)d_in[5];   // [1024,32]
  const float* b_dt   = (const float*)d_in[6];   // [1024]
  const float* A_log  = (const float*)d_in[7];   // [1024,64]
  const float* Dp     = (const float*)d_in[8];   // [1024]
  const float* w_out  = (const float*)d_in[9];   // [512,1024]
  const float* w1 = (const float*)d_in[10];      // [512,120000]
  const float* b1 = (const float*)d_in[11];
  const float* w2 = (const float*)d_in[12];      // [256,512]
  const float* b2 = (const float*)d_in[13];
  const float* w3 = (const float*)d_in[14];      // [64,256]
  const float* b3 = (const float*)d_in[15];
  const float* w4 = (const float*)d_in[16];      // [8,64]
  const float* b4 = (const float*)d_in[17];
  float* out = (float*)d_out;

  float* ws   = (float*)d_ws;
  float* xz   = ws;                 // [2000][2048]  (x-half becomes gated-y later)
  float* xc   = xz + 4096000;       // [2000][1024]
  float* dtb  = xc + 2048000;       // [2000][1024]
  float* ym   = dtb + 2048000;      // [2000][480]
  float* yfl  = ym + 960000;        // [8][120000]
  float* xdbl = yfl + 960000;       // [2000][160]
  float* r1   = xdbl + 320000;      // [8][512]
  float* r2   = r1 + 4096;          // [8][256]

  // zero the atomic accumulators (xdbl + r1, contiguous)
  hipMemsetAsync(xdbl, 0, (320000 + 4096) * sizeof(float), stream);

  // 1. in_proj: xz[2000][2048] = x[2000][480] @ Win[2048][512(^480)]^T
  gemm_nt<64, 128, 32, 4, 8><<<dim3(2048 / 128, (BL + 63) / 64, 1), 256, 0, stream>>>(
      x, w_in, xz, nullptr, BL, 2048, KIN, KIN, 512, 2048, 0);

  // 2. depthwise conv + silu
  conv_silu<<<(BL * 1024) / 256, 256, 0, stream>>>(xz, conv_w, conv_b, xc);

  // 3. x_proj (split-K=2, atomic): xdbl[2000][160] = xc @ Wxp^T
  gemm_nt<32, 64, 32, 1, 8><<<dim3(3, (BL + 31) / 32, 2), 256, 0, stream>>>(
      xc, w_xp, xdbl, nullptr, BL, 160, 1024, 1024, 1024, 160, 3);

  // 4. dt_proj + softplus: dtb[2000][1024] = softplus(xdbl[:, :32] @ Wdt^T + b_dt)
  gemm_nt<32, 64, 32, 1, 8><<<dim3(1024 / 64, (BL + 31) / 32, 1), 256, 0, stream>>>(
      xdbl, w_dt, dtb, b_dt, BL, 1024, 32, 160, 32, 1024, 1);

  // 5. selective scan -> gated y into xz x-half
  scan_kernel<<<512, 256, 0, stream>>>(dtb, xc, xdbl, xz, A_log, Dp);

  // 6. out_proj + selu: ym[2000][480] = selu(yg @ Wout[480 rows]^T)
  gemm_nt<64, 64, 32, 4, 4><<<dim3((KIN + 63) / 64, (BL + 63) / 64, 1), 256, 0, stream>>>(
      xz, w_out, ym, nullptr, BL, KIN, 1024, 2048, 1024, KIN, 2);

  // 7. permute to y_flat
  transpose_k<<<(8 * NFLAT) / 256, 256, 0, stream>>>(ym, yfl);

  // 8. fc1 (atomic accumulate into r1)
  fc1_kernel<<<512, 256, 0, stream>>>(yfl, w1, r1);

  // 9. fc2
  fc2_kernel<<<512, 256, 0, stream>>>(r1, b1, w2, b2, r2);

  // 10. fc3 + fc4
  fc34_kernel<<<1, 256, 0, stream>>>(r2, w3, b3, w4, b4, out);
}